// Round 1
// 1126.804 us; speedup vs baseline: 1.3934x; 1.3934x over previous
//
#include <hip/hip_runtime.h>
#include <hip/hip_bf16.h>
#include <stdint.h>

#define IN_F   4096
#define OUT_F  11008
#define M_TOT  8192
#define ZCOLS  (OUT_F / 8)      // 1376
#define KK_ROWS (IN_F / 8)      // 512

#define BM 256
#define BN 256
#define BK 64
#define NT (IN_F / BK)          // 64 K-tiles
#define GRID_M (M_TOT / BM)     // 32
#define GRID_N (OUT_F / BN)     // 43
#define NWG (GRID_M * GRID_N)   // 1376 (divisible by 8)
#define CPX (NWG / 8)           // 172

typedef __attribute__((ext_vector_type(8))) short  bf16x8;
typedef __attribute__((ext_vector_type(8))) ushort ushort8;
typedef __attribute__((ext_vector_type(4))) float  f32x4;

__device__ __forceinline__ ushort f2bf(float f) {
    __hip_bfloat16 h = __float2bfloat16(f);   // RTNE
    return *reinterpret_cast<ushort*>(&h);
}

// ---------------- Phase 1: x fp32 -> bf16 (8 floats / thread, 16B store) ----
__global__ void convert_x(const float4* __restrict__ x, ushort8* __restrict__ xb) {
    size_t t = (size_t)blockIdx.x * 256 + threadIdx.x;   // 4,194,304 threads
    float4 a = x[2 * t];
    float4 b = x[2 * t + 1];
    ushort8 o;
    o[0] = f2bf(a.x); o[1] = f2bf(a.y); o[2] = f2bf(a.z); o[3] = f2bf(a.w);
    o[4] = f2bf(b.x); o[5] = f2bf(b.y); o[6] = f2bf(b.z); o[7] = f2bf(b.w);
    xb[t] = o;
}

// ---------------- Phase 2: dequant -> Wt [N][K] bf16 (unchanged) -----------
__global__ void dequant_w(const int* __restrict__ qw, const int* __restrict__ qz,
                          const float* __restrict__ sc, ushort* __restrict__ wt) {
    int t  = blockIdx.x * 256 + threadIdx.x;       // 5,636,096 threads total
    int n  = t >> 9;
    int kk = t & 511;
    int g  = kk >> 4;
    int w  = qw[kk * OUT_F + n];
    int z  = (qz[g * ZCOLS + (n >> 3)] >> ((n & 7) * 4)) & 15;
    float s = sc[g * OUT_F + n];
    ushort r[8];
#pragma unroll
    for (int i = 0; i < 8; ++i) {
        int q = (w >> (4 * i)) & 15;
        r[i] = f2bf((float)(q - z) * s);
    }
    ushort4* dst = (ushort4*)(wt + (size_t)n * IN_F + kk * 8);
    dst[0] = make_ushort4(r[0], r[1], r[2], r[3]);
    dst[1] = make_ushort4(r[4], r[5], r[6], r[7]);
}

// ---------------- Phase 3: 256x256 8-phase GEMM, C = A @ Bt^T + bias -------
// A  [M, K] bf16 row-major; Bt [N, K] bf16 row-major (W^T); C [M, N] fp32
//
// LDS: smem[8][8192] ushorts = 128 KiB.
//   region index = buf*4 + mat*2 + half   (mat: 0=A, 1=B)
//   A half mh holds rows {wm*128 + mh*64 + 0..63} for wm=0,1 -> 128 rows x 64 k
//   B half nh holds cols {wn*64 + nh*32 + 0..31} for wn=0..3 -> 128 rows x 64 k
//   linear [128][64]; logical element (r,c) lives at byte (r*128 + (c*2 ^ ((r&7)<<4)))
//   -> global_load_lds writes LINEAR dest; source address is pre-inverse-swizzled.
__global__ __launch_bounds__(512, 2)
void gemm_bf16(const ushort* __restrict__ A, const ushort* __restrict__ Bt,
               const float* __restrict__ bias, float* __restrict__ C) {
    __shared__ ushort smem[8][8192];   // 128 KiB

    const int tid  = threadIdx.x;
    const int wave = tid >> 6;
    const int lane = tid & 63;

    // T1: XCD-aware bijective swizzle (nwg % 8 == 0)
    const int bid = blockIdx.x;
    const int swz = (bid & 7) * CPX + (bid >> 3);
    const int bm0 = (swz / GRID_N) * BM;
    const int bn0 = (swz % GRID_N) * BN;

    const int wm = wave >> 2;     // 0..1  (M half of C-tile)
    const int wn = wave & 3;      // 0..3  (N quarter)
    const int lm = lane & 15;
    const int lq = lane >> 4;

    // ---- staging constants (inverse-swizzled global source) ----
    const int sr   = lane >> 3;                    // 0..7 (row within 8-row group)
    const int scol = 8 * ((lane & 7) ^ sr);        // swizzled col, ushort units

    const ushort* aSrc[2][2];   // [mh][j]
    const ushort* bSrc[2][2];   // [nh][j]
#pragma unroll
    for (int j = 0; j < 2; ++j) {
        const int r = wave * 16 + j * 8 + sr;      // region-linear row 0..127
#pragma unroll
        for (int h = 0; h < 2; ++h) {
            aSrc[h][j] = A  + (size_t)(bm0 + ((r >> 6) << 7) + h * 64 + (r & 63)) * IN_F + scol;
            bSrc[h][j] = Bt + (size_t)(bn0 + ((r >> 5) << 6) + h * 32 + (r & 31)) * IN_F + scol;
        }
    }

    // ---- ds_read column offsets (swizzled), ushort units ----
    const int cswz0 = (lq * 8)      ^ ((lm & 7) << 3);   // ks=0
    const int cswz1 = (32 + lq * 8) ^ ((lm & 7) << 3);   // ks=1

    f32x4  acc[8][4] = {};
    bf16x8 af[4][2];
    bf16x8 bfv[2][2];

#define STAGE_A(buf, mh, kt) do {                                                        \
    _Pragma("unroll")                                                                    \
    for (int j_ = 0; j_ < 2; ++j_)                                                       \
        __builtin_amdgcn_global_load_lds(                                                \
            (const __attribute__((address_space(1))) void*)(aSrc[mh][j_] + (size_t)(kt) * BK), \
            (__attribute__((address_space(3))) void*)(&smem[(buf) * 4 + (mh)][(wave * 2 + j_) * 512]), \
            16, 0, 0);                                                                   \
} while (0)

#define STAGE_B(buf, nh, kt) do {                                                        \
    _Pragma("unroll")                                                                    \
    for (int j_ = 0; j_ < 2; ++j_)                                                       \
        __builtin_amdgcn_global_load_lds(                                                \
            (const __attribute__((address_space(1))) void*)(bSrc[nh][j_] + (size_t)(kt) * BK), \
            (__attribute__((address_space(3))) void*)(&smem[(buf) * 4 + 2 + (nh)][(wave * 2 + j_) * 512]), \
            16, 0, 0);                                                                   \
} while (0)

#define LDA(buf, mh) do {                                                                \
    const ushort* ab_ = &smem[(buf) * 4 + (mh)][wm * 4096 + lm * 64];                    \
    _Pragma("unroll")                                                                    \
    for (int i_ = 0; i_ < 4; ++i_) {                                                     \
        af[i_][0] = *(const bf16x8*)(ab_ + i_ * 1024 + cswz0);                           \
        af[i_][1] = *(const bf16x8*)(ab_ + i_ * 1024 + cswz1);                           \
    }                                                                                    \
} while (0)

#define LDB(buf, nh) do {                                                                \
    const ushort* bb_ = &smem[(buf) * 4 + 2 + (nh)][wn * 2048 + lm * 64];                \
    _Pragma("unroll")                                                                    \
    for (int j_ = 0; j_ < 2; ++j_) {                                                     \
        bfv[j_][0] = *(const bf16x8*)(bb_ + j_ * 1024 + cswz0);                          \
        bfv[j_][1] = *(const bf16x8*)(bb_ + j_ * 1024 + cswz1);                          \
    }                                                                                    \
} while (0)

#define MFMA_Q(mh, nh) do {                                                              \
    __builtin_amdgcn_s_setprio(1);                                                       \
    _Pragma("unroll")                                                                    \
    for (int i_ = 0; i_ < 4; ++i_)                                                       \
        _Pragma("unroll")                                                                \
        for (int j_ = 0; j_ < 2; ++j_)                                                   \
            _Pragma("unroll")                                                            \
            for (int k_ = 0; k_ < 2; ++k_)                                               \
                acc[(mh) * 4 + i_][(nh) * 2 + j_] = __builtin_amdgcn_mfma_f32_16x16x32_bf16( \
                    af[i_][k_], bfv[j_][k_], acc[(mh) * 4 + i_][(nh) * 2 + j_], 0, 0, 0); \
    __builtin_amdgcn_s_setprio(0);                                                       \
} while (0)

#define BAR()   asm volatile("s_barrier" ::: "memory")
#define LGKM0() asm volatile("s_waitcnt lgkmcnt(0)" ::: "memory")
#define VM(n)   asm volatile("s_waitcnt vmcnt(" #n ")" ::: "memory")

    // ---- prologue: tile0 {A0,B1,A1,B0} + tile1 {A0,B1,A1}; 14 loads, keep 6 in flight
    STAGE_A(0, 0, 0);
    STAGE_B(0, 1, 0);
    STAGE_A(0, 1, 0);
    STAGE_B(0, 0, 0);
    STAGE_A(1, 0, 1);
    STAGE_B(1, 1, 1);
    STAGE_A(1, 1, 1);
    VM(6);
    BAR();

#pragma unroll 1
    for (int it = 0; it < NT / 2; ++it) {
        const int t1 = 2 * it + 1;
        int s2 = 2 * it + 2; if (s2 > NT - 1) s2 = NT - 1;   // clamp: uniform inst count
        int s3 = 2 * it + 3; if (s3 > NT - 1) s3 = NT - 1;

        // ph1: buf0 (mh0,nh0); stage B0(t1)->buf1
        LDA(0, 0); LDB(0, 0);
        STAGE_B(1, 0, t1);
        BAR(); LGKM0();
        MFMA_Q(0, 0);
        BAR();

        // ph2: buf0 (mh0,nh1), reuse A frags; stage A0(s2)->buf0
        LDB(0, 1);
        STAGE_A(0, 0, s2);
        BAR(); LGKM0();
        MFMA_Q(0, 1);
        BAR();

        // ph3: buf0 (mh1,nh1), reuse B frags; stage B1(s2)->buf0
        LDA(0, 1);
        STAGE_B(0, 1, s2);
        BAR(); LGKM0();
        MFMA_Q(1, 1);
        BAR();

        // ph4: buf0 (mh1,nh0), reuse A frags; stage A1(s2)->buf0; counted vmcnt
        LDB(0, 0);
        STAGE_A(0, 1, s2);
        BAR(); LGKM0();
        MFMA_Q(1, 0);
        VM(6);
        BAR();

        // ph5: buf1 (mh0,nh0); stage B0(s2)->buf0
        LDA(1, 0); LDB(1, 0);
        STAGE_B(0, 0, s2);
        BAR(); LGKM0();
        MFMA_Q(0, 0);
        BAR();

        // ph6: buf1 (mh0,nh1); stage A0(s3)->buf1
        LDB(1, 1);
        STAGE_A(1, 0, s3);
        BAR(); LGKM0();
        MFMA_Q(0, 1);
        BAR();

        // ph7: buf1 (mh1,nh1); stage B1(s3)->buf1
        LDA(1, 1);
        STAGE_B(1, 1, s3);
        BAR(); LGKM0();
        MFMA_Q(1, 1);
        BAR();

        // ph8: buf1 (mh1,nh0); stage A1(s3)->buf1; counted vmcnt
        LDB(1, 0);
        STAGE_A(1, 1, s3);
        BAR(); LGKM0();
        MFMA_Q(1, 0);
        VM(6);
        BAR();
    }

    VM(0);   // drain outstanding prefetches before epilogue

    // epilogue: row = bm0 + wm*128 + mt*16 + lq*4 + r, col = bn0 + wn*64 + nt*16 + lm
    const int cm0 = bm0 + wm * 128 + lq * 4;
    const int cn0 = bn0 + wn * 64 + lm;
#pragma unroll
    for (int nt2 = 0; nt2 < 4; ++nt2) {
        const int n = cn0 + nt2 * 16;
        const float bv = bias[n];
#pragma unroll
        for (int mt = 0; mt < 8; ++mt) {
            float* out = C + (size_t)(cm0 + mt * 16) * OUT_F + n;
#pragma unroll
            for (int r = 0; r < 4; ++r)
                out[(size_t)r * OUT_F] = acc[mt][nt2][r] + bv;
        }
    }

#undef STAGE_A
#undef STAGE_B
#undef LDA
#undef LDB
#undef MFMA_Q
#undef BAR
#undef LGKM0
#undef VM
}

extern "C" void kernel_launch(void* const* d_in, const int* in_sizes, int n_in,
                              void* d_out, int out_size, void* d_ws, size_t ws_size,
                              hipStream_t stream) {
    const float* x       = (const float*)d_in[0];  // [4,2048,4096]
    const float* scales  = (const float*)d_in[1];  // [32,11008]
    const float* bias    = (const float*)d_in[2];  // [11008]
    const int*   qweight = (const int*)d_in[3];    // [512,11008]
    const int*   qzeros  = (const int*)d_in[4];    // [32,1376]
    float* out = (float*)d_out;                    // [8192,11008]

    // workspace: xb (67,108,864 B) | wt (90,177,536 B)
    ushort* xb = (ushort*)d_ws;
    ushort* wt = (ushort*)((char*)d_ws + (size_t)M_TOT * IN_F * 2);

    convert_x<<<(M_TOT * IN_F / 8) / 256, 256, 0, stream>>>((const float4*)x, (ushort8*)xb);
    dequant_w<<<(OUT_F * KK_ROWS) / 256, 256, 0, stream>>>(qweight, qzeros, scales, wt);
    gemm_bf16<<<NWG, 512, 0, stream>>>(xb, wt, bias, out);
}